// Round 7
// baseline (404.160 us; speedup 1.0000x reference)
//
#include <hip/hip_runtime.h>

// Problem constants (fixed by reference setup_inputs)
#define B   4
#define C   64      // input channels
#define D   64      // dims per head of q/k/v
#define NN  25      // angRes*angRes angular positions
#define HW  4096    // h*w
#define F   (D*HW)  // 262144 feature dim per head, flattened

typedef unsigned short ushort_t;
typedef unsigned int   uint_t;
typedef __attribute__((ext_vector_type(8)))  short  short8;   // 8 bf16 (4 VGPRs)
typedef __attribute__((ext_vector_type(16))) float  floatx16; // MFMA 32x32 accum
typedef __attribute__((ext_vector_type(4)))  float  f32x4;
typedef __attribute__((ext_vector_type(4)))  unsigned short us4;

// Compensated bf16 weight splits (W = hi + lo, |err| ~ 2^-17 rel), native
// [row][c] layout. Rows 0..127 = q,k; Wv rows 0..63 = v.
__device__ ushort_t g_Wthi[128 * C];
__device__ ushort_t g_Wtlo[128 * C];
__device__ ushort_t g_Wvhi[D * C];
__device__ ushort_t g_Wvlo[D * C];

// Tiny cross-kernel accumulators (20KB).
__device__ float g_S[B * NN * NN];
__device__ float g_qq[B * NN];
__device__ float g_kk[B * NN];
__device__ float g_attT[B * NN * NN];   // transposed att [b][m][n]

static __device__ __forceinline__ ushort_t f2bf(float f) {
    uint_t u = __float_as_uint(f);
    u += 0x7FFFu + ((u >> 16) & 1u);   // round-to-nearest-even
    return (ushort_t)(u >> 16);
}
static __device__ __forceinline__ float bf2f(ushort_t h) {
    return __uint_as_float((uint_t)h << 16);
}

// ---- K0: zero S/qq/kk ----
__global__ void k_zero() {
    int i = blockIdx.x * 256 + threadIdx.x;
    if (i < 2500)      g_S[i] = 0.f;
    else if (i < 2600) g_qq[i - 2500] = 0.f;
    else if (i < 2700) g_kk[i - 2600] = 0.f;
}

// ---- Kw: split all 192 W rows into bf16 hi/lo (native layout). ----
__global__ void k_wprep(const float* __restrict__ W) {
    int i = blockIdx.x * 256 + threadIdx.x;          // over 192*64
    if (i < 128 * 64) {
        float w = W[i];                              // W[d'][c], native index
        ushort_t hi = f2bf(w);
        g_Wthi[i] = hi;
        g_Wtlo[i] = f2bf(w - bf2f(hi));
    } else if (i < 192 * 64) {
        float w = W[i];                              // v rows 128..191
        int j = i - 128 * 64;
        ushort_t hi = f2bf(w);
        g_Wvhi[j] = hi;
        g_Wvlo[j] = f2bf(w - bf2f(hi));
    }
}

// ---- K1: fused projection + S-contribution. Q/K NEVER touch HBM.
// grid (HW/32, 2, B) = 1024 blocks, 512 thr = 8 waves, 100KB LDS,
// bounds(512,2) -> 1 block/CU (8 waves), 256-VGPR budget.
// Block = (p-slice of 32, d-slab of 32, b). Wave w owns n = w, w+8, w+16
// (+24 for w=0): loads x B-fragments straight from global (2x128B
// segments/instr), converts to compensated hi/lo bf16 in-reg, runs the
// 3-pass MFMA for Q,K,V (36 MFMA/n). Q/K rounded rows -> LDS tiles
// (XOR-swizzled 16B granules); V -> HBM packed. After one barrier the
// block computes S[n][m] += Q.K over its 1024-f slice (8 MFMA/wave,
// k-split by wave) and atomically adds -- the old k_sqk, minus its
// 104MB write + 134MB re-read.
__global__ void __launch_bounds__(512, 2)
k_projS(const float* __restrict__ x, float* __restrict__ V) {
    __shared__ ushort_t sQ[25 * 1024];   // [n][f-slice 1024] bf16, swizzled
    __shared__ ushort_t sK[25 * 1024];

    const int t    = threadIdx.x;
    const int w    = t >> 6, ln = t & 63;
    const int slab = blockIdx.y, b = blockIdx.z;
    const int p0   = blockIdx.x * 32;
    const int row  = ln & 31, kh = ln >> 5, kh8 = kh * 8;
    const size_t cstride = (size_t)NN * HW;
    // x[b][c][n][p0+row]; add n*HW + c*cstride per element
    const float* xp = x + ((size_t)(b * C) * NN) * HW + p0 + row;

    float xbufA[32], xbufB[32];
    // preload n = w  (always valid: w <= 7 < 25)
#pragma unroll
    for (int ks = 0; ks < 4; ++ks)
#pragma unroll
        for (int j = 0; j < 8; ++j)
            xbufA[ks * 8 + j] =
                xp[(size_t)(ks * 16 + kh8 + j) * cstride + (size_t)w * HW];

#pragma unroll
    for (int i = 0; i < 4; ++i) {
        const int n = w + i * 8;
        if (n > 24) break;                       // wave-uniform
        const int n2 = n + 8;
        float (&cur)[32] = (i & 1) ? xbufB : xbufA;   // compile-time ping-pong
        float (&nxt)[32] = (i & 1) ? xbufA : xbufB;
        if (n2 <= 24) {                          // prefetch next n early
#pragma unroll
            for (int ks = 0; ks < 4; ++ks)
#pragma unroll
                for (int j = 0; j < 8; ++j)
                    nxt[ks * 8 + j] =
                        xp[(size_t)(ks * 16 + kh8 + j) * cstride + (size_t)n2 * HW];
        }

        // W fragments per iteration (16KB total, L1-hot) to cap VGPR.
        short8 qhi[4], qlo[4], khi[4], klo[4], vhi[4], vlo[4];
#pragma unroll
        for (int ks = 0; ks < 4; ++ks) {
            const int off = ks * 16 + kh8;
            qhi[ks] = *(const short8*)&g_Wthi[(slab * 32 + row) * 64 + off];
            qlo[ks] = *(const short8*)&g_Wtlo[(slab * 32 + row) * 64 + off];
            khi[ks] = *(const short8*)&g_Wthi[(64 + slab * 32 + row) * 64 + off];
            klo[ks] = *(const short8*)&g_Wtlo[(64 + slab * 32 + row) * 64 + off];
            vhi[ks] = *(const short8*)&g_Wvhi[(slab * 32 + row) * 64 + off];
            vlo[ks] = *(const short8*)&g_Wvlo[(slab * 32 + row) * 64 + off];
        }

        // x -> compensated hi/lo bf16 B-fragments (in-register, no LDS)
        short8 bhi[4], blo[4];
#pragma unroll
        for (int ks = 0; ks < 4; ++ks)
#pragma unroll
            for (int j = 0; j < 8; ++j) {
                const float v = cur[ks * 8 + j];
                const ushort_t hi = f2bf(v);
                bhi[ks][j] = (short)hi;
                blo[ks][j] = (short)f2bf(v - bf2f(hi));
            }

        floatx16 aQ, aK, aV;
#pragma unroll
        for (int r = 0; r < 16; ++r) { aQ[r] = 0.f; aK[r] = 0.f; aV[r] = 0.f; }
#pragma unroll
        for (int ks = 0; ks < 4; ++ks) {
            aQ = __builtin_amdgcn_mfma_f32_32x32x16_bf16(qhi[ks], bhi[ks], aQ, 0, 0, 0);
            aQ = __builtin_amdgcn_mfma_f32_32x32x16_bf16(qlo[ks], bhi[ks], aQ, 0, 0, 0);
            aQ = __builtin_amdgcn_mfma_f32_32x32x16_bf16(qhi[ks], blo[ks], aQ, 0, 0, 0);
            aK = __builtin_amdgcn_mfma_f32_32x32x16_bf16(khi[ks], bhi[ks], aK, 0, 0, 0);
            aK = __builtin_amdgcn_mfma_f32_32x32x16_bf16(klo[ks], bhi[ks], aK, 0, 0, 0);
            aK = __builtin_amdgcn_mfma_f32_32x32x16_bf16(khi[ks], blo[ks], aK, 0, 0, 0);
            aV = __builtin_amdgcn_mfma_f32_32x32x16_bf16(vhi[ks], bhi[ks], aV, 0, 0, 0);
            aV = __builtin_amdgcn_mfma_f32_32x32x16_bf16(vlo[ks], bhi[ks], aV, 0, 0, 0);
            aV = __builtin_amdgcn_mfma_f32_32x32x16_bf16(vhi[ks], blo[ks], aV, 0, 0, 0);
        }

        // epilogue: norms (pre-rounding fp32), Q/K -> LDS, V -> HBM packed.
        // f-enum within slice: f = r4*256 + ln*4 + j; 16B granule g = f>>3
        // = r4*32 + (ln>>1), XOR-swizzled by (n&7) -> S-phase reads at the
        // structural 4-way b128 minimum instead of 32-way.
        float nq = 0.f, nk = 0.f;
#pragma unroll
        for (int r4 = 0; r4 < 4; ++r4) {
            us4 hq, hk; f32x4 vv;
#pragma unroll
            for (int j = 0; j < 4; ++j) {
                const float q = aQ[r4 * 4 + j], k = aK[r4 * 4 + j];
                nq += q * q; nk += k * k;
                hq[j] = f2bf(q); hk[j] = f2bf(k);
                vv[j] = aV[r4 * 4 + j];
            }
            const int lx = n * 1024 + ((r4 * 32 + (ln >> 1)) ^ (n & 7)) * 8
                         + (ln & 1) * 4;
            *(us4*)&sQ[lx] = hq;
            *(us4*)&sK[lx] = hk;
            // V packed: chunk c0 = (pslice*2+slab)*4+r4, elem ln*4+j
            *(f32x4*)&V[((size_t)(b * NN + n)) * F
                        + (size_t)((blockIdx.x * 2 + slab) * 4 + r4) * 256
                        + ln * 4] = vv;
        }
        for (int off = 32; off > 0; off >>= 1) {
            nq += __shfl_xor(nq, off);
            nk += __shfl_xor(nk, off);
        }
        if (ln == 0) {
            atomicAdd(&g_qq[b * NN + n], nq);
            atomicAdd(&g_kk[b * NN + n], nk);
        }
    }
    __syncthreads();

    // ---- S phase: wave w owns 16-f k-steps s = w*8 .. w*8+7 over the
    // 1024-f slice. A = Q rows (n), B = K rows (m); pad rows clamp to 24
    // (outputs discarded by guard). Granule g = s*2 + kh, read with the
    // same (row&7) XOR used at write time.
    {
        const int rc = (row < NN) ? row : (NN - 1);
        floatx16 acc;
#pragma unroll
        for (int r = 0; r < 16; ++r) acc[r] = 0.f;
#pragma unroll
        for (int i = 0; i < 8; ++i) {
            const int g  = (w * 8 + i) * 2 + kh;
            const int lx = rc * 1024 + (g ^ (rc & 7)) * 8;
            short8 aq = *(const short8*)&sQ[lx];
            short8 bk = *(const short8*)&sK[lx];
            acc = __builtin_amdgcn_mfma_f32_32x32x16_bf16(aq, bk, acc, 0, 0, 0);
        }
        __syncthreads();                      // all S reads done
        float (*redS)[64][17] = (float (*)[64][17])sQ;   // overlay (34.8KB)
#pragma unroll
        for (int r = 0; r < 16; ++r) redS[w][ln][r] = acc[r];
        __syncthreads();
        if (w == 0) {
#pragma unroll
            for (int r = 0; r < 16; ++r) {
                float v = 0.f;
#pragma unroll
                for (int wv = 0; wv < 8; ++wv) v += redS[wv][ln][r];
                const int srow = (r & 3) + 8 * (r >> 2) + 4 * (ln >> 5);
                const int scol = ln & 31;
                if (srow < NN && scol < NN)
                    atomicAdd(&g_S[((size_t)b * NN + srow) * NN + scol], v);
            }
        }
    }
}

// ---- K3: normalize logits + softmax over m; writes TRANSPOSED att.
__global__ void k_softmax() {
    const int b = blockIdx.x, n = threadIdx.x;
    if (n >= NN) return;
    const float qn = fmaxf(sqrtf(g_qq[b * NN + n]), 1e-12f);
    float l[NN], mx = -1e30f;
#pragma unroll
    for (int m = 0; m < NN; ++m) {
        const float km = fmaxf(sqrtf(g_kk[b * NN + m]), 1e-12f);
        l[m] = g_S[((size_t)b * NN + n) * NN + m] / (qn * km);
        mx = fmaxf(mx, l[m]);
    }
    float s = 0.f;
#pragma unroll
    for (int m = 0; m < NN; ++m) { l[m] = expf(l[m] - mx); s += l[m]; }
    const float inv = 1.f / s;
#pragma unroll
    for (int m = 0; m < NN; ++m) g_attT[((size_t)b * NN + m) * NN + n] = l[m] * inv;
}

// ---- K4: out[b,d,n,p] = sum_m att[n,m] * V[b,m,(d,p)], packed-V form.
// grid (F/1024, B). Thread owns 4 consecutive packed g (= one lane-chunk
// of a k_projS store): f32x4 loads fully coalesced; acc = 25 x f32x4.
// decode: c0 = g>>8 = [pslice(128)][slab(2)][r4(4)], lane part = g&255.
__global__ void __launch_bounds__(256, 4)
k_outmix(const float* __restrict__ V, float* __restrict__ out) {
    const int tid = blockIdx.x * 256 + threadIdx.x;   // 0..65535 per b
    const int b   = blockIdx.y;
    const float* Vb = V + (size_t)b * NN * F + (size_t)tid * 4;
    const float* at = g_attT + b * NN * NN;

    f32x4 acc[NN];
#pragma unroll
    for (int n = 0; n < NN; ++n) acc[n] = 0.f;
#pragma unroll 5
    for (int m = 0; m < NN; ++m) {
        const f32x4 v = *(const f32x4*)(Vb + (size_t)m * F);
#pragma unroll
        for (int n = 0; n < NN; ++n) acc[n] += at[m * NN + n] * v;
    }

    const int ln = tid & 63, c0 = tid >> 6;
    const int r4 = c0 & 3, slab = (c0 >> 2) & 1, ps = c0 >> 3;
    const int p  = ps * 32 + (ln & 31);
    const int db = slab * 32 + 8 * r4 + 4 * (ln >> 5);  // rows db..db+3 (j)
#pragma unroll
    for (int n = 0; n < NN; ++n)
#pragma unroll
        for (int j = 0; j < 4; ++j)
            out[((size_t)(b * D + db + j) * NN + n) * HW + p] = acc[n][j];
}

extern "C" void kernel_launch(void* const* d_in, const int* in_sizes, int n_in,
                              void* d_out, int out_size, void* d_ws, size_t ws_size,
                              hipStream_t stream) {
    const float* x = (const float*)d_in[0];
    const float* W = (const float*)d_in[1];
    float* outf = (float*)d_out;

    // V fp32 = 104,857,600 B -> d_ws. Q/K live only in LDS now.
    float* V = (float*)d_ws;

    k_zero   <<<dim3(11),           256, 0, stream>>>();
    k_wprep  <<<dim3(48),           256, 0, stream>>>(W);
    k_projS  <<<dim3(HW/32, 2, B),  512, 0, stream>>>(x, V);
    k_softmax<<<dim3(B),             64, 0, stream>>>();
    k_outmix <<<dim3(F/1024, B),    256, 0, stream>>>(V, outf);
}